// Round 14
// baseline (131.089 us; speedup 1.0000x reference)
//
#include <hip/hip_runtime.h>
#include <hip/hip_fp16.h>
#include <math.h>

#define Bn 512
#define Ln 200
#define En 64
#define Hn 4
#define Dn 16
#define NT13 13           // ceil(200/16)
#define KS3 18            // Kh row stride (halves): 36 B = 9 words (odd -> conflict-free)
#define VS3 200           // Vt row stride (halves): 100 words (2-way = free)
#define QSC 0.36067376022224085f   // 0.25 * log2(e): folds softmax exp into 2^x

typedef _Float16 __f16;
typedef __f16 f16x4 __attribute__((ext_vector_type(4)));
typedef __f16 f16x8 __attribute__((ext_vector_type(8)));
typedef float f32x4 __attribute__((ext_vector_type(4)));

#if __has_builtin(__builtin_amdgcn_exp2f)
__device__ __forceinline__ float fexp2(float x) { return __builtin_amdgcn_exp2f(x); }
#else
__device__ __forceinline__ float fexp2(float x) { return exp2f(x); }
#endif

__device__ __forceinline__ f16x8 pack8s(float4 a, float4 b, float4 pa, float4 pb) {
    f16x8 r;
    r[0] = (__f16)(a.x + pa.x); r[1] = (__f16)(a.y + pa.y);
    r[2] = (__f16)(a.z + pa.z); r[3] = (__f16)(a.w + pa.w);
    r[4] = (__f16)(b.x + pb.x); r[5] = (__f16)(b.y + pb.y);
    r[6] = (__f16)(b.z + pb.z); r[7] = (__f16)(b.w + pb.w);
    return r;
}
__device__ __forceinline__ f16x8 pack8(float4 a, float4 b) {
    f16x8 r;
    r[0] = (__f16)a.x; r[1] = (__f16)a.y; r[2] = (__f16)a.z; r[3] = (__f16)a.w;
    r[4] = (__f16)b.x; r[5] = (__f16)b.y; r[6] = (__f16)b.z; r[7] = (__f16)b.w;
    return r;
}

// ============ Fully fused: proj + attention + pool + Wf. Block = (b, ONE head), 256 thr ============
// R14: latency-epoch collapse.
//  - Wave w owns tiles {4w..4w+3}: ALL its x/pos loads issue up-front (one vmcnt epoch,
//    16 independent b128s in flight) instead of per-tile dependent chains.
//  - No first barrier: proj is len-independent (fixed 13-tile assignment); mask popcount
//    runs concurrently; ONE __syncthreads total before attention.
//  - Q never in LDS: swapped-operand proj mfma(A=W, B=x) -> C[ch][t] lane layout IS the
//    attention S^T B-operand layout (16x16x32 A/B fragment symmetry); wave's q-quad ==
//    its own proj tiles, so qf lives in registers. Qh deleted (LDS 15.4 KB).
//  - Softmax denominator via ones-MFMA rowsum (R13). Wf epilogue fused (atomicAdd).
__global__ __launch_bounds__(256, 3) void fused_kernel(
    const float* __restrict__ input, const int* __restrict__ mask,
    const float* __restrict__ pos_enc,
    const float* __restrict__ Wk, const float* __restrict__ bk,
    const float* __restrict__ Wv, const float* __restrict__ bv,
    const float* __restrict__ Wq, const float* __restrict__ bq,
    const float* __restrict__ Wf, const float* __restrict__ bf_,
    float* __restrict__ out)
{
    __shared__ __align__(16) __f16 Kh[Ln * KS3];    // 7.2 KB  K[t][16]
    __shared__ __align__(16) __f16 Vt[16 * VS3];    // 6.4 KB  V^T[vd][t]
    __shared__ float red[4][16];
    __shared__ float ph[16];
    __shared__ int cnt_red[4];

    const int tid  = threadIdx.x;
    const int b    = blockIdx.x >> 2, h = blockIdx.x & 3;
    const int wave = tid >> 6, lane = tid & 63;
    const int quad = lane >> 4, ln16 = lane & 15;

    // ---- mask load (reduced later; no barrier here) ----
    const int mv = (tid < Ln) ? mask[b * Ln + tid] : 0;

    // ---- issue ALL own-tile x/pos loads up-front: one global-latency epoch ----
    const float4* in4 = (const float4*)(input + (size_t)b * Ln * En);
    const float4* pe4 = (const float4*)pos_enc;
    f16x8 af[4][2];
    #pragma unroll
    for (int i = 0; i < 4; ++i) {
        const int rt = 4 * wave + i;
        const int R  = rt * 16 + ln16;
        const bool rok = (rt < NT13) && (R < Ln);
        #pragma unroll
        for (int ks = 0; ks < 2; ++ks) {
            float4 xa = {0,0,0,0}, xb = {0,0,0,0}, pa = {0,0,0,0}, pb = {0,0,0,0};
            if (rok) {
                const int o4 = R * 16 + ks * 8 + quad * 2;
                xa = in4[o4]; xb = in4[o4 + 1];
                pa = pe4[o4]; pb = pe4[o4 + 1];
            }
            af[i][ks] = pack8s(xa, xb, pa, pb);
        }
    }

    // ---- weight fragments (L2-hot) + biases ----
    f16x8 bfr[3][2];
    #pragma unroll
    for (int m = 0; m < 3; ++m) {
        const float* W = (m == 0) ? Wk : (m == 1) ? Wv : Wq;
        #pragma unroll
        for (int ks = 0; ks < 2; ++ks) {
            const float4* wp = (const float4*)(W + (size_t)(h * 16 + ln16) * 64) + (ks * 8 + quad * 2);
            bfr[m][ks] = pack8(wp[0], wp[1]);
        }
    }
    const int cg = h * 16 + ln16;
    const float bkv = bk[cg], bvv = bv[cg];
    const float4 bq4 = ((const float4*)bq)[h * 4 + quad];   // Q bias for channels quad*4+j

    // ---- projection of own tiles; K,V -> LDS, Q -> registers (swapped operands) ----
    f16x4 qf[4];
    #pragma unroll
    for (int i = 0; i < 4; ++i) {
        const int rt = 4 * wave + i;
        if (rt < NT13) {
            f32x4 ak = {0,0,0,0}, av = {0,0,0,0}, aq = {0,0,0,0};
            #pragma unroll
            for (int ks = 0; ks < 2; ++ks) {
                ak = __builtin_amdgcn_mfma_f32_16x16x32_f16(af[i][ks], bfr[0][ks], ak, 0, 0, 0);
                av = __builtin_amdgcn_mfma_f32_16x16x32_f16(af[i][ks], bfr[1][ks], av, 0, 0, 0);
                aq = __builtin_amdgcn_mfma_f32_16x16x32_f16(bfr[2][ks], af[i][ks], aq, 0, 0, 0); // swapped
            }
            #pragma unroll
            for (int j = 0; j < 4; ++j) {
                const int t = rt * 16 + quad * 4 + j;
                if (t < Ln) Kh[t * KS3 + ln16] = (__f16)(ak[j] + bkv);
            }
            const int vc0 = rt * 16 + quad * 4;
            if (vc0 < Ln) {
                f16x4 vp;
                #pragma unroll
                for (int j = 0; j < 4; ++j) vp[j] = (__f16)(av[j] + bvv);
                *(f16x4*)(Vt + ln16 * VS3 + vc0) = vp;
            }
            // Q: C[ch=quad*4+j][t=ln16] -> lane ln16 = query rt*16+ln16, regs j = channel
            qf[i][0] = (__f16)((aq[0] + bq4.x) * QSC);
            qf[i][1] = (__f16)((aq[1] + bq4.y) * QSC);
            qf[i][2] = (__f16)((aq[2] + bq4.z) * QSC);
            qf[i][3] = (__f16)((aq[3] + bq4.w) * QSC);
        } else {
            qf[i] = (f16x4){(__f16)0.f, (__f16)0.f, (__f16)0.f, (__f16)0.f};
        }
    }

    // ---- mask popcount (concurrent with proj; published by the single barrier) ----
    int c = (mv != 0) ? 1 : 0;
    #pragma unroll
    for (int off = 32; off; off >>= 1) c += __shfl_down(c, off, 64);
    if (lane == 0) cnt_red[wave] = c;
    __syncthreads();   // K/V LDS + cnt_red visible (the ONLY pre-attention barrier)
    const int len = cnt_red[0] + cnt_red[1] + cnt_red[2] + cnt_red[3];
    const int nt = (len + 15) >> 4;

    // ---- attention: wave w's q-quad = its own tiles {4w..4w+3}; all keys per wave ----
    const bool active = (4 * wave < nt);
    const f16x4 ones = {(__f16)1.f, (__f16)1.f, (__f16)1.f, (__f16)1.f};
    f32x4 o2[4], lacc[4];
    #pragma unroll
    for (int i = 0; i < 4; ++i) { o2[i] = (f32x4){0,0,0,0}; lacc[i] = (f32x4){0,0,0,0}; }

    if (active) {
        f16x4 kf = *(const f16x4*)(Kh + ln16 * KS3 + quad * 4);
        f16x4 vf = *(const f16x4*)(Vt + ln16 * VS3 + quad * 4);

        for (int kt = 0; kt < nt - 1; ++kt) {   // full tiles: no masking
            const int krn = min((kt + 1) * 16 + ln16, Ln - 1);
            const int vcn = min((kt + 1) * 16 + quad * 4, Ln - 4);
            const f16x4 kfn = *(const f16x4*)(Kh + krn * KS3 + quad * 4);
            const f16x4 vfn = *(const f16x4*)(Vt + ln16 * VS3 + vcn);
            f32x4 s[4];
            #pragma unroll
            for (int i = 0; i < 4; ++i)
                s[i] = __builtin_amdgcn_mfma_f32_16x16x16f16(kf, qf[i], (f32x4){0,0,0,0}, 0, 0, 0);
            f16x4 pf[4];
            #pragma unroll
            for (int i = 0; i < 4; ++i) {
                #pragma unroll
                for (int j = 0; j < 4; ++j)
                    pf[i][j] = (__f16)fexp2(fminf(s[i][j], 14.5f));   // 2^14.5 < fp16 max
            }
            #pragma unroll
            for (int i = 0; i < 4; ++i) {
                o2[i]   = __builtin_amdgcn_mfma_f32_16x16x16f16(vf,   pf[i], o2[i],   0, 0, 0);
                lacc[i] = __builtin_amdgcn_mfma_f32_16x16x16f16(ones, pf[i], lacc[i], 0, 0, 0);  // rowsum
            }
            kf = kfn; vf = vfn;
        }
        {   // last tile: zero keys >= len
            const int kbase = (nt - 1) * 16 + quad * 4;
            f32x4 s[4];
            #pragma unroll
            for (int i = 0; i < 4; ++i)
                s[i] = __builtin_amdgcn_mfma_f32_16x16x16f16(kf, qf[i], (f32x4){0,0,0,0}, 0, 0, 0);
            f16x4 pf[4];
            #pragma unroll
            for (int i = 0; i < 4; ++i) {
                #pragma unroll
                for (int j = 0; j < 4; ++j) {
                    const bool kok = (kbase + j) < len;
                    pf[i][j] = kok ? (__f16)fexp2(fminf(s[i][j], 14.5f)) : (__f16)0.f;
                }
            }
            #pragma unroll
            for (int i = 0; i < 4; ++i) {
                o2[i]   = __builtin_amdgcn_mfma_f32_16x16x16f16(vf,   pf[i], o2[i],   0, 0, 0);
                lacc[i] = __builtin_amdgcn_mfma_f32_16x16x16f16(ones, pf[i], lacc[i], 0, 0, 0);
            }
        }
    }

    // ---- normalize + pool (lacc[i][0] = l[q=ln16], replicated by ones-MFMA) ----
    f32x4 pool = {0.f, 0.f, 0.f, 0.f};
    if (active) {
        #pragma unroll
        for (int i = 0; i < 4; ++i) {
            const float rs = ((4 * wave + i) * 16 + ln16 < len) ? 1.f / lacc[i][0] : 0.f;
            #pragma unroll
            for (int j = 0; j < 4; ++j) pool[j] = fmaf(o2[i][j], rs, pool[j]);
        }
    }

    // ---- reduce pool over 16 q-lanes; combine 4 waves; write ----
    #pragma unroll
    for (int j = 0; j < 4; ++j) {
        #pragma unroll
        for (int off = 1; off < 16; off <<= 1) pool[j] += __shfl_xor(pool[j], off, 64);
    }
    if (ln16 == 0) {
        #pragma unroll
        for (int j = 0; j < 4; ++j) red[wave][quad * 4 + j] = pool[j];
    }
    __syncthreads();
    if (tid < 16)
        ph[tid] = (red[0][tid] + red[1][tid] + red[2][tid] + red[3][tid]) / ((float)len + 1e-8f);
    __syncthreads();

    // ---- fused final projection: partial out[b,e] over i in [h*16, h*16+16) ----
    if (tid < 64) {
        const int e = tid;
        const float* wr = Wf + (size_t)e * 64 + h * 16;
        float a = (h == 0) ? bf_[e] : 0.f;
        #pragma unroll
        for (int i = 0; i < 16; ++i) a = fmaf(wr[i], ph[i], a);
        atomicAdd(out + b * En + e, a);
    }
}

extern "C" void kernel_launch(void* const* d_in, const int* in_sizes, int n_in,
                              void* d_out, int out_size, void* d_ws, size_t ws_size,
                              hipStream_t stream) {
    const float* input   = (const float*)d_in[0];
    const int*   mask    = (const int*)  d_in[1];
    const float* pos_enc = (const float*)d_in[2];
    const float* Wk      = (const float*)d_in[3];
    const float* bk      = (const float*)d_in[4];
    const float* Wv      = (const float*)d_in[5];
    const float* bv      = (const float*)d_in[6];
    const float* Wq      = (const float*)d_in[7];
    const float* bq      = (const float*)d_in[8];
    const float* Wf      = (const float*)d_in[9];
    const float* bf      = (const float*)d_in[10];

    float* out = (float*)d_out;
    hipMemsetAsync(out, 0, (size_t)Bn * En * sizeof(float), stream);   // zero accumulator

    fused_kernel<<<Bn * Hn, 256, 0, stream>>>(input, mask, pos_enc,
                                              Wk, bk, Wv, bv, Wq, bq, Wf, bf, out);
}